// Round 6
// baseline (1782.629 us; speedup 1.0000x reference)
//
#include <hip/hip_runtime.h>
#include <hip/hip_bf16.h>
#include <cstdint>

#define B_   8
#define N_   512
#define HID_ 512
#define H_   8
#define D_   64
#define E_   32

typedef unsigned short u16;
typedef unsigned int   u32;
typedef float  float2_t __attribute__((ext_vector_type(2)));
typedef float  float4_t __attribute__((ext_vector_type(4)));
typedef u32    uint4v   __attribute__((ext_vector_type(4)));
typedef __bf16 bf16x8   __attribute__((ext_vector_type(8)));

__device__ __forceinline__ float b2f(u16 u) {
    return __uint_as_float(((u32)u) << 16);
}
__device__ __forceinline__ u16 f2b(float f) {
    u32 b = __float_as_uint(f);
    b += 0x7fffu + ((b >> 16) & 1u);   // RNE
    return (u16)(b >> 16);
}
__device__ __forceinline__ u32 pk2(float a, float b) {
    return (u32)f2b(a) | ((u32)f2b(b) << 16);
}
__device__ __forceinline__ void unp8(uint4v u, float* f) {
    f[0] = __uint_as_float(u[0] << 16); f[1] = __uint_as_float(u[0] & 0xffff0000u);
    f[2] = __uint_as_float(u[1] << 16); f[3] = __uint_as_float(u[1] & 0xffff0000u);
    f[4] = __uint_as_float(u[2] << 16); f[5] = __uint_as_float(u[2] & 0xffff0000u);
    f[6] = __uint_as_float(u[3] << 16); f[7] = __uint_as_float(u[3] & 0xffff0000u);
}

// ---------------------------------------------------------------------------
// GEMM (bf16 MFMA, fp32 accum): out[M=4096, n] = X[4096,512] @ W[512,n] + bias
// kind==0: X fp32, fused QKV, grid.y=24 (0-7 -> q fp32, 8-15 -> k(+ct_key) bf16
//          in BLOCKED layout kb[b][h][c][n][z] (d = c*8+z) so attn logits
//          loads are coalesced, 16-23 -> v bf16)
// kind==1: X bf16 (attn out in ws), O-projection, grid.y=8, writes fp32 d_out
// ---------------------------------------------------------------------------
__global__ __launch_bounds__(256) void gemm_kernel(
    const float* __restrict__ Xf, const u16* __restrict__ Xb,
    const float* __restrict__ W0, const float* __restrict__ W1, const float* __restrict__ W2,
    const float* __restrict__ Bq, const float* __restrict__ Bk, const float* __restrict__ Bv,
    float* __restrict__ qout, u16* __restrict__ kout, u16* __restrict__ vout,
    float* __restrict__ fout,
    const float* __restrict__ ctk, const int* __restrict__ ct, int kind)
{
    __shared__ u16 lx[128 * 40];   // [m][k] bf16, stride 40 (80B rows, 16B aligned)
    __shared__ u16 lw[64 * 40];    // [n][k] bf16 (W transposed), stride 40

    const int t  = threadIdx.x;
    const int m0 = blockIdx.x * 128;
    const int n0g = blockIdx.y * 64;

    int mode, cl0;
    const float* W; const float* Bi;
    if (kind == 0) {
        mode = n0g >> 9; cl0 = n0g & 511;
        W  = (mode == 0) ? W0 : ((mode == 1) ? W1 : W2);
        Bi = (mode == 0) ? Bq : ((mode == 1) ? Bk : Bv);
    } else {
        mode = 3; cl0 = n0g; W = W0; Bi = Bq;
    }

    const int wv = t >> 6, lane = t & 63, quad = lane >> 4, l16 = lane & 15;

    float4_t acc[2][4];
    #pragma unroll
    for (int mi = 0; mi < 2; ++mi)
        #pragma unroll
        for (int ni = 0; ni < 4; ++ni) {
            float4_t z = {0.f, 0.f, 0.f, 0.f};
            acc[mi][ni] = z;
        }

    for (int k0 = 0; k0 < 512; k0 += 32) {
        if (kind == 0) {
            #pragma unroll
            for (int half = 0; half < 2; ++half) {
                const int c = t + half * 256;
                const int r = c >> 2, ck = c & 3;
                const float* src = &Xf[(m0 + r) * 512 + k0 + ck * 8];
                float4_t a0 = *(const float4_t*)src;
                float4_t a1 = *(const float4_t*)(src + 4);
                uint4v p;
                p[0] = pk2(a0[0], a0[1]); p[1] = pk2(a0[2], a0[3]);
                p[2] = pk2(a1[0], a1[1]); p[3] = pk2(a1[2], a1[3]);
                *(uint4v*)&lx[r * 40 + ck * 8] = p;
            }
        } else {
            #pragma unroll
            for (int half = 0; half < 2; ++half) {
                const int c = t + half * 256;
                const int r = c >> 2, ck = c & 3;
                *(uint4v*)&lx[r * 40 + ck * 8] =
                    *(const uint4v*)&Xb[(m0 + r) * 512 + k0 + ck * 8];
            }
        }
        {
            const int kl = t >> 3, nc = t & 7;
            const float* src = &W[(k0 + kl) * 512 + cl0 + nc * 8];
            float4_t wa = *(const float4_t*)src;
            float4_t wb = *(const float4_t*)(src + 4);
            lw[(nc * 8 + 0) * 40 + kl] = f2b(wa[0]);
            lw[(nc * 8 + 1) * 40 + kl] = f2b(wa[1]);
            lw[(nc * 8 + 2) * 40 + kl] = f2b(wa[2]);
            lw[(nc * 8 + 3) * 40 + kl] = f2b(wa[3]);
            lw[(nc * 8 + 4) * 40 + kl] = f2b(wb[0]);
            lw[(nc * 8 + 5) * 40 + kl] = f2b(wb[1]);
            lw[(nc * 8 + 6) * 40 + kl] = f2b(wb[2]);
            lw[(nc * 8 + 7) * 40 + kl] = f2b(wb[3]);
        }
        __syncthreads();

        bf16x8 af[2], bfr[4];
        af[0] = *(bf16x8*)&lx[(wv * 32 +      l16) * 40 + quad * 8];
        af[1] = *(bf16x8*)&lx[(wv * 32 + 16 + l16) * 40 + quad * 8];
        #pragma unroll
        for (int ni = 0; ni < 4; ++ni)
            bfr[ni] = *(bf16x8*)&lw[(ni * 16 + l16) * 40 + quad * 8];

        #pragma unroll
        for (int mi = 0; mi < 2; ++mi)
            #pragma unroll
            for (int ni = 0; ni < 4; ++ni)
                acc[mi][ni] = __builtin_amdgcn_mfma_f32_16x16x32_bf16(af[mi], bfr[ni], acc[mi][ni], 0, 0, 0);
        __syncthreads();
    }

    const int b_blk = m0 >> 9;
    #pragma unroll
    for (int ni = 0; ni < 4; ++ni) {
        const int cl = cl0 + ni * 16 + l16;
        const float bias = Bi[cl];
        float ctkv = 0.f;
        if (mode == 1) ctkv = ctk[ct[b_blk] * HID_ + cl];
        #pragma unroll
        for (int mi = 0; mi < 2; ++mi) {
            #pragma unroll
            for (int reg = 0; reg < 4; ++reg) {
                const int gm = m0 + wv * 32 + mi * 16 + quad * 4 + reg;
                float val = acc[mi][ni][reg] + bias;
                if (mode == 0)      qout[gm * 512 + cl] = val * 0.125f;
                else if (mode == 1) {
                    // blocked K: kb[b][h][c][n][z], d = c*8+z
                    const int nn = gm & 511, bb = gm >> 9;
                    const int hh = cl >> 6, cc = (cl >> 3) & 7, zz = cl & 7;
                    kout[((((bb * 8 + hh) * 8 + cc) * 512) + nn) * 8 + zz] = f2b(val + ctkv);
                }
                else if (mode == 2) vout[gm * 512 + cl] = f2b(val);
                else                fout[gm * 512 + cl] = val;
            }
        }
    }
}

// ---------------------------------------------------------------------------
// Edge MLP via MFMA: eb[p,h] = elu(ef[p,:]@We1+be1)@We2+be2, p in [0,2M).
// ---------------------------------------------------------------------------
__global__ __launch_bounds__(256) void edge_kernel(
    const float* __restrict__ ef,
    const float* __restrict__ We1, const float* __restrict__ be1,
    const float* __restrict__ We2, const float* __restrict__ be2,
    u16* __restrict__ eb)
{
    __shared__ u16 lw1[64 * 32];       // B1[n=hidden][k=e]  (We1 transposed)
    __shared__ u16 lw2[16 * 64];       // B2[n=out(8 valid)][k=hidden] (We2^T, padded)
    __shared__ u16 h1t[4][16 * 72];    // per-wave H1 tile [row][k], stride 72 (144B, 16B-aligned)

    const int t = threadIdx.x;
    const int wv = t >> 6, lane = t & 63, quad = lane >> 4, l16 = lane & 15;

    for (int i = t; i < 2048; i += 256) {
        const int n = i >> 5, k = i & 31;
        lw1[n * 32 + k] = f2b(We1[k * 64 + n]);
    }
    for (int i = t; i < 1024; i += 256) {
        const int n = i >> 6, k = i & 63;
        lw2[n * 64 + k] = (n < 8) ? f2b(We2[k * 8 + n]) : (u16)0;
    }
    __syncthreads();

    bf16x8 b1[4];
    #pragma unroll
    for (int ni = 0; ni < 4; ++ni)
        b1[ni] = *(bf16x8*)&lw1[(ni * 16 + l16) * 32 + quad * 8];
    bf16x8 b20 = *(bf16x8*)&lw2[l16 * 64 +      quad * 8];
    bf16x8 b21 = *(bf16x8*)&lw2[l16 * 64 + 32 + quad * 8];

    float be1r[4];
    #pragma unroll
    for (int ni = 0; ni < 4; ++ni) be1r[ni] = be1[l16 + 16 * ni];
    const float be2r = (l16 < 8) ? be2[l16] : 0.f;

    for (int tt = 0; tt < 4; ++tt) {
        const long row0g = (long)blockIdx.x * 256 + tt * 64 + wv * 16;

        // A1 frag straight from global (coalesced dwordx4), fp32 -> bf16
        const float* ap = ef + (row0g + l16) * 32 + quad * 8;
        float4_t f0 = *(const float4_t*)ap;
        float4_t f1 = *(const float4_t*)(ap + 4);
        uint4v au;
        au[0] = pk2(f0[0], f0[1]); au[1] = pk2(f0[2], f0[3]);
        au[2] = pk2(f1[0], f1[1]); au[3] = pk2(f1[2], f1[3]);
        bf16x8 a1 = *(bf16x8*)&au;

        float4_t zero = {0.f, 0.f, 0.f, 0.f};
        float4_t c1[4];
        #pragma unroll
        for (int ni = 0; ni < 4; ++ni)
            c1[ni] = __builtin_amdgcn_mfma_f32_16x16x32_bf16(a1, b1[ni], zero, 0, 0, 0);

        // bias + ELU, write H1 tile (own-wave private region)
        #pragma unroll
        for (int ni = 0; ni < 4; ++ni) {
            #pragma unroll
            for (int reg = 0; reg < 4; ++reg) {
                float v = c1[ni][reg] + be1r[ni];
                v = (v > 0.f) ? v : expm1f(v);
                h1t[wv][(quad * 4 + reg) * 72 + l16 + 16 * ni] = f2b(v);
            }
        }
        __syncthreads();

        // Layer2: A2 from H1 tile (A-layout), two K=32 MFMAs
        bf16x8 a20 = *(bf16x8*)&h1t[wv][l16 * 72 +      quad * 8];
        bf16x8 a21 = *(bf16x8*)&h1t[wv][l16 * 72 + 32 + quad * 8];
        float4_t c2 = zero;
        c2 = __builtin_amdgcn_mfma_f32_16x16x32_bf16(a20, b20, c2, 0, 0, 0);
        c2 = __builtin_amdgcn_mfma_f32_16x16x32_bf16(a21, b21, c2, 0, 0, 0);

        if (l16 < 8) {
            #pragma unroll
            for (int reg = 0; reg < 4; ++reg)
                eb[(row0g + quad * 4 + reg) * 8 + l16] = f2b(c2[reg] + be2r);
        }
        __syncthreads();
    }
}

// ---------------------------------------------------------------------------
// Attention v6: 256 threads (validated 52-VGPR codegen base), blocked K.
// Round-6 changes (target: per-wave LDS-issue count + load ILP — the two
// structure-level quantities unchanged across r2..r5's invariant 266 us):
//  * jj-unrolled x2: both keys (t, t+256) in one pass -> Q broadcast
//    ds_read_b128 halved (512->256/wave), 2 K-loads in flight per c-step,
//    32 fma per c (was 16) so load latency is self-covered.
//  * normalization fused: softmax writes unnormalized exp + sinv[2][8]=1/Z;
//    3rd softmax pass eliminated; max-pass values kept in 16 regs so the
//    exp pass re-read is eliminated too (-96 LDS ops/thread).
//  * mean/PV multiply by sinv from regs (4x b128 read once per thread).
// Numerics: mean path arithmetically identical (multiply-before-sum kept);
// PV scales after accumulation (ulp-level, output is bf16 anyway).
// Tripwire: WRITE_SIZE > 13 MB = spills.
// ---------------------------------------------------------------------------
__global__ __launch_bounds__(256, 4) void attn_kernel(
    const float* __restrict__ qws, const u16* __restrict__ kws, const u16* __restrict__ vws,
    const u16* __restrict__ ebws,
    const int* __restrict__ bmask, const int* __restrict__ pmask,
    u16* __restrict__ attn_out, float* __restrict__ mean_out)
{
    __shared__ float ql[2 * 512];
    __shared__ float S[2][8][512];
    __shared__ float sinv[2][8];

    const int t = threadIdx.x;
    const int b = blockIdx.x >> 8;
    const int i0 = (blockIdx.x & 255) * 2;
    const int row0 = b * N_ + i0;

    *(float4_t*)&ql[t * 4] = *(const float4_t*)&qws[row0 * 512 + t * 4];

    const int padi0 = pmask[b * N_ + i0];
    const int padi1 = pmask[b * N_ + i0 + 1];
    __syncthreads();

    // ---- logits: both keys (t, t+256) in one pass ----
    {
        const int jj = t, jk = t + 256;
        const int pj0 = pmask[b * N_ + jj];
        const int pj1 = pmask[b * N_ + jk];
        const int bmA0 = bmask[row0 * 512 + jj];
        const int bmA1 = bmask[row0 * 512 + jk];
        const int bmB0 = bmask[(row0 + 1) * 512 + jj];
        const int bmB1 = bmask[(row0 + 1) * 512 + jk];
        const bool m00 = (padi0 | pj0 | bmA0) != 0;   // row0, key jj
        const bool m01 = (padi0 | pj1 | bmA1) != 0;   // row0, key jk
        const bool m10 = (padi1 | pj0 | bmB0) != 0;   // row1, key jj
        const bool m11 = (padi1 | pj1 | bmB1) != 0;   // row1, key jk

        const u16* ep0  = ebws + ((long)row0       * 512 + jj) * 8;
        const u16* ep1  = ebws + ((long)(row0 + 1) * 512 + jj) * 8;
        const u16* kb   = kws + (long)b * 262144 + jj * 8;   // key jj; key jk at +2048

        #pragma unroll 1
        for (int h = 0; h < 8; ++h) {
            float d00 = 0.f, d10 = 0.f;   // key jj, rows 0/1
            float d01 = 0.f, d11 = 0.f;   // key jk, rows 0/1
            #pragma unroll
            for (int c = 0; c < 8; ++c) {
                uint4v uA = *(const uint4v*)(kb + (h * 8 + c) * 4096);
                uint4v uB = *(const uint4v*)(kb + (h * 8 + c) * 4096 + 2048);
                float kfA[8], kfB[8]; unp8(uA, kfA); unp8(uB, kfB);
                const float4_t qa = *(const float4_t*)&ql[h * 64 + c * 8];
                const float4_t qb = *(const float4_t*)&ql[h * 64 + c * 8 + 4];
                const float4_t qc = *(const float4_t*)&ql[512 + h * 64 + c * 8];
                const float4_t qd = *(const float4_t*)&ql[512 + h * 64 + c * 8 + 4];
                #pragma unroll
                for (int z = 0; z < 4; ++z) {
                    d00 = fmaf(kfA[z], qa[z], d00); d00 = fmaf(kfA[z + 4], qb[z], d00);
                    d10 = fmaf(kfA[z], qc[z], d10); d10 = fmaf(kfA[z + 4], qd[z], d10);
                    d01 = fmaf(kfB[z], qa[z], d01); d01 = fmaf(kfB[z + 4], qb[z], d01);
                    d11 = fmaf(kfB[z], qc[z], d11); d11 = fmaf(kfB[z + 4], qd[z], d11);
                }
            }
            S[0][h][jj] = m00 ? -__builtin_inff() : (d00 + b2f(ep0[h]));
            S[0][h][jk] = m01 ? -__builtin_inff() : (d01 + b2f(ep0[h + 2048]));
            S[1][h][jj] = m10 ? -__builtin_inff() : (d10 + b2f(ep1[h]));
            S[1][h][jk] = m11 ? -__builtin_inff() : (d11 + b2f(ep1[h + 2048]));
        }
    }
    __syncthreads();

    // ---- softmax per (row, head): unnormalized exp + 1/Z; values cached in regs ----
    {
        const int h = t >> 5, l = t & 31;
        #pragma unroll
        for (int r = 0; r < 2; ++r) {
            float v[16];
            #pragma unroll
            for (int kk = 0; kk < 16; ++kk) v[kk] = S[r][h][l + 32 * kk];
            float m = v[0];
            #pragma unroll
            for (int kk = 1; kk < 16; ++kk) m = fmaxf(m, v[kk]);
            #pragma unroll
            for (int off = 16; off >= 1; off >>= 1) m = fmaxf(m, __shfl_xor(m, off, 32));

            float zsum = 0.f;
            #pragma unroll
            for (int kk = 0; kk < 16; ++kk) {
                const float e = (v[kk] == -__builtin_inff()) ? 0.f : __expf(v[kk] - m);
                S[r][h][l + 32 * kk] = e;
                zsum += e;
            }
            #pragma unroll
            for (int off = 16; off >= 1; off >>= 1) zsum += __shfl_xor(zsum, off, 32);

            if (l == 0) sinv[r][h] = (zsum > 0.f) ? (1.f / zsum) : 0.f;
        }
    }
    __syncthreads();

    // sinv -> regs (4x b128 per thread), reused by mean and PV
    float4_t iv[4];
    #pragma unroll
    for (int q = 0; q < 4; ++q) iv[q] = *(const float4_t*)&sinv[0][0 + q * 4];

    // ---- attn mean over heads: both keys per thread ----
    {
        #pragma unroll
        for (int half = 0; half < 2; ++half) {
            const int jj = t + half * 256;
            #pragma unroll
            for (int r = 0; r < 2; ++r) {
                float sum = 0.f;
                #pragma unroll
                for (int h = 0; h < 8; ++h)
                    sum += S[r][h][jj] * iv[(r * 8 + h) >> 2][(r * 8 + h) & 3];
                mean_out[(long)(row0 + r) * 512 + jj] = sum * 0.125f;
            }
        }
    }

    // ---- PV (V-loads coalesced; final scale by 1/Z from regs) ----
    {
        const int h = t >> 5, d0 = (t & 31) * 2;
        const float iv0 = iv[h >> 2][h & 3];
        const float iv1 = iv[(8 + h) >> 2][(8 + h) & 3];
        float a00 = 0.f, a01 = 0.f, a10 = 0.f, a11 = 0.f;
        const u16* vp = vws + (long)(b * N_) * 512 + h * 64 + d0;
        #pragma unroll 1
        for (int j = 0; j < 512; j += 4) {
            const float4_t p0 = *(const float4_t*)&S[0][h][j];
            const float4_t p1 = *(const float4_t*)&S[1][h][j];
            #pragma unroll
            for (int z = 0; z < 4; ++z) {
                const u32 u = *(const u32*)(vp + (long)(j + z) * 512);
                const float v0 = __uint_as_float(u << 16);
                const float v1 = __uint_as_float(u & 0xffff0000u);
                a00 = fmaf(p0[z], v0, a00); a01 = fmaf(p0[z], v1, a01);
                a10 = fmaf(p1[z], v0, a10); a11 = fmaf(p1[z], v1, a11);
            }
        }
        *(u32*)&attn_out[(long)row0       * 512 + h * 64 + d0] = pk2(a00 * iv0, a01 * iv0);
        *(u32*)&attn_out[(long)(row0 + 1) * 512 + h * 64 + d0] = pk2(a10 * iv1, a11 * iv1);
    }
}

// ---------------------------------------------------------------------------
// Fallback fused attention for small ws_size (kept in sync with blocked K).
// ---------------------------------------------------------------------------
__global__ __launch_bounds__(256) void attn_fused_kernel(
    const float* __restrict__ qws, const u16* __restrict__ kws, const u16* __restrict__ vws,
    const float* __restrict__ ef,
    const float* __restrict__ We1, const float* __restrict__ be1,
    const float* __restrict__ We2, const float* __restrict__ be2,
    const int* __restrict__ bmask, const int* __restrict__ pmask,
    u16* __restrict__ attn_out, float* __restrict__ mean_out)
{
    __shared__ float ql[2 * 512];
    __shared__ float S[2][8][512];
    __shared__ __align__(16) float wf[2632];

    const int t = threadIdx.x;
    const int b = blockIdx.x >> 8;
    const int i0 = (blockIdx.x & 255) * 2;
    const int row0 = b * N_ + i0;

    for (int i = t; i < 2632; i += 256) {
        float v;
        if (i < 2048)      v = We1[i];
        else if (i < 2112) v = be1[i - 2048];
        else if (i < 2624) v = We2[i - 2112];
        else               v = be2[i - 2624];
        wf[i] = v;
    }
    *(float4_t*)&ql[t * 4] = *(const float4_t*)&qws[row0 * 512 + t * 4];

    const int padi0 = pmask[b * N_ + i0];
    const int padi1 = pmask[b * N_ + i0 + 1];
    __syncthreads();

    const float4_t* We1v = (const float4_t*)wf;
    const float4_t* be1v = (const float4_t*)(wf + 2048);
    const float4_t* We2v = (const float4_t*)(wf + 2112);
    const float4_t* be2v = (const float4_t*)(wf + 2624);

    for (int jj = t; jj < 512; jj += 256) {
        const int pj  = pmask[b * N_ + jj];
        const int bm0 = bmask[row0 * 512 + jj];
        const int bm1 = bmask[(row0 + 1) * 512 + jj];
        const bool msk0 = (padi0 | pj | bm0) != 0;
        const bool msk1 = (padi1 | pj | bm1) != 0;

        float x0[32], x1[32];
        {
            const float4_t* p0 = (const float4_t*)(ef + ((long)row0       * 512 + jj) * 32);
            const float4_t* p1 = (const float4_t*)(ef + ((long)(row0 + 1) * 512 + jj) * 32);
            #pragma unroll
            for (int c = 0; c < 8; ++c) {
                float4_t a = p0[c], bb = p1[c];
                #pragma unroll
                for (int z = 0; z < 4; ++z) { x0[c * 4 + z] = a[z]; x1[c * 4 + z] = bb[z]; }
            }
        }

        float e0[8], e1[8];
        {
            float4_t o0a = be2v[0], o0b = be2v[1];
            float4_t o1a = o0a,     o1b = o0b;
            #pragma unroll 1
            for (int o4 = 0; o4 < 16; ++o4) {
                float4_t h0 = be1v[o4], h1 = h0;
                #pragma unroll
                for (int e = 0; e < 32; ++e) {
                    const float4_t w = We1v[e * 16 + o4];
                    const float xe0 = x0[e], xe1 = x1[e];
                    #pragma unroll
                    for (int z = 0; z < 4; ++z) {
                        h0[z] = fmaf(xe0, w[z], h0[z]);
                        h1[z] = fmaf(xe1, w[z], h1[z]);
                    }
                }
                #pragma unroll
                for (int z = 0; z < 4; ++z) {
                    h0[z] = (h0[z] > 0.f) ? h0[z] : expm1f(h0[z]);
                    h1[z] = (h1[z] > 0.f) ? h1[z] : expm1f(h1[z]);
                }
                #pragma unroll
                for (int z = 0; z < 4; ++z) {
                    const int o = o4 * 4 + z;
                    const float4_t wa = We2v[o * 2], wb = We2v[o * 2 + 1];
                    #pragma unroll
                    for (int p = 0; p < 4; ++p) {
                        o0a[p] = fmaf(h0[z], wa[p], o0a[p]);
                        o0b[p] = fmaf(h0[z], wb[p], o0b[p]);
                        o1a[p] = fmaf(h1[z], wa[p], o1a[p]);
                        o1b[p] = fmaf(h1[z], wb[p], o1b[p]);
                    }
                }
            }
            #pragma unroll
            for (int p = 0; p < 4; ++p) {
                e0[p] = o0a[p]; e0[p + 4] = o0b[p];
                e1[p] = o1a[p]; e1[p + 4] = o1b[p];
            }
        }

        const u16* kb = kws + (long)b * 262144 + jj * 8;
        #pragma unroll 1
        for (int h = 0; h < 8; ++h) {
            float d0 = 0.f, d1 = 0.f;
            #pragma unroll
            for (int c = 0; c < 8; ++c) {
                uint4v u = *(const uint4v*)(kb + (h * 8 + c) * 4096);
                float kf[8]; unp8(u, kf);
                const float* q0 = &ql[h * 64 + c * 8];
                const float* q1 = &ql[512 + h * 64 + c * 8];
                #pragma unroll
                for (int z = 0; z < 8; ++z) {
                    d0 = fmaf(kf[z], q0[z], d0);
                    d1 = fmaf(kf[z], q1[z], d1);
                }
            }
            S[0][h][jj] = msk0 ? -__builtin_inff() : (d0 + e0[h]);
            S[1][h][jj] = msk1 ? -__builtin_inff() : (d1 + e1[h]);
        }
    }
    __syncthreads();

    {
        const int h = t >> 5, l = t & 31;
        #pragma unroll
        for (int r = 0; r < 2; ++r) {
            float m = -__builtin_inff();
            for (int kk = 0; kk < 16; ++kk) m = fmaxf(m, S[r][h][l + 32 * kk]);
            #pragma unroll
            for (int off = 16; off >= 1; off >>= 1) m = fmaxf(m, __shfl_xor(m, off, 32));

            float zsum = 0.f;
            for (int kk = 0; kk < 16; ++kk) {
                const int j = l + 32 * kk;
                const float s = S[r][h][j];
                const float e = (s == -__builtin_inff()) ? 0.f : __expf(s - m);
                S[r][h][j] = e;
                zsum += e;
            }
            #pragma unroll
            for (int off = 16; off >= 1; off >>= 1) zsum += __shfl_xor(zsum, off, 32);

            const float inv = (zsum > 0.f) ? (1.f / zsum) : 0.f;
            for (int kk = 0; kk < 16; ++kk) S[r][h][l + 32 * kk] *= inv;
        }
    }
    __syncthreads();

    for (int jj = t; jj < 512; jj += 256) {
        #pragma unroll
        for (int r = 0; r < 2; ++r) {
            float sum = 0.f;
            #pragma unroll
            for (int h = 0; h < 8; ++h) sum += S[r][h][jj];
            mean_out[(long)(row0 + r) * 512 + jj] = sum * 0.125f;
        }
    }

    {
        const int h = t >> 5, d0 = (t & 31) * 2;
        float a00 = 0.f, a01 = 0.f, a10 = 0.f, a11 = 0.f;
        const u16* vp = vws + (long)(b * N_) * 512 + h * 64 + d0;
        #pragma unroll 4
        for (int j = 0; j < 512; ++j) {
            const u32 u = *(const u32*)(vp + (long)j * 512);
            const float v0 = __uint_as_float(u << 16);
            const float v1 = __uint_as_float(u & 0xffff0000u);
            const float p0 = S[0][h][j];
            const float p1 = S[1][h][j];
            a00 = fmaf(p0, v0, a00); a01 = fmaf(p0, v1, a01);
            a10 = fmaf(p1, v0, a10); a11 = fmaf(p1, v1, a11);
        }
        *(u32*)&attn_out[(long)row0       * 512 + h * 64 + d0] = pk2(a00, a01);
        *(u32*)&attn_out[(long)(row0 + 1) * 512 + h * 64 + d0] = pk2(a10, a11);
    }
}

// ---------------------------------------------------------------------------
extern "C" void kernel_launch(void* const* d_in, const int* in_sizes, int n_in,
                              void* d_out, int out_size, void* d_ws, size_t ws_size,
                              hipStream_t stream) {
    const float* x   = (const float*)d_in[0];
    const int*   ct  = (const int*)d_in[1];
    const float* ef  = (const float*)d_in[2];
    const int*   bm  = (const int*)d_in[3];
    const int*   pm  = (const int*)d_in[4];
    const float* Wq  = (const float*)d_in[5];  const float* bq = (const float*)d_in[6];
    const float* Wk  = (const float*)d_in[7];  const float* bk = (const float*)d_in[8];
    const float* Wv  = (const float*)d_in[9];  const float* bv = (const float*)d_in[10];
    const float* Wo  = (const float*)d_in[11]; const float* bo = (const float*)d_in[12];
    const float* We1 = (const float*)d_in[13]; const float* be1 = (const float*)d_in[14];
    const float* We2 = (const float*)d_in[15]; const float* be2 = (const float*)d_in[16];
    const float* ctk = (const float*)d_in[17];
    // d_in[18] = ct_bias_emb: constant along softmax axis -> cancels; unused.

    char* ws = (char*)d_ws;
    float* qws  = (float*)ws;                    //  8,388,608 B (fp32, pre-scaled)
    u16*   kws  = (u16*)(ws + 8388608);          //  4,194,304 B (bf16, +ct_key, BLOCKED)
    u16*   vws  = (u16*)(ws + 12582912);         //  4,194,304 B
    u16*   aout = (u16*)(ws + 16777216);         //  4,194,304 B (attn out, bf16)
    u16*   ebws = (u16*)(ws + 20971520);         // 33,554,432 B (edge bias, bf16)
    const size_t WS_BIG = 54525952;

    float* out0 = (float*)d_out;        // (B,N,HID) fp32
    float* out1 = out0 + 2097152;       // (B,N,N)  fp32 attn mean

    gemm_kernel<<<dim3(32, 24), 256, 0, stream>>>(x, nullptr, Wq, Wk, Wv, bq, bk, bv,
                                                  qws, kws, vws, out0, ctk, ct, 0);
    if (ws_size >= WS_BIG) {
        edge_kernel<<<8192, 256, 0, stream>>>(ef, We1, be1, We2, be2, ebws);
        attn_kernel<<<2048, 256, 0, stream>>>(qws, kws, vws, ebws, bm, pm, aout, out1);
    } else {
        attn_fused_kernel<<<2048, 256, 0, stream>>>(qws, kws, vws, ef, We1, be1, We2, be2,
                                                    bm, pm, aout, out1);
    }
    gemm_kernel<<<dim3(32, 8), 256, 0, stream>>>(nullptr, aout, Wo, Wo, Wo, bo, bo, bo,
                                                 qws, kws, vws, out0, ctk, ct, 1);
}

// Round 7
// 565.463 us; speedup vs baseline: 3.1525x; 3.1525x over previous
//
#include <hip/hip_runtime.h>
#include <hip/hip_bf16.h>
#include <cstdint>

#define B_   8
#define N_   512
#define HID_ 512
#define H_   8
#define D_   64
#define E_   32

typedef unsigned short u16;
typedef unsigned int   u32;
typedef float  float4_t __attribute__((ext_vector_type(4)));
typedef u32    uint4v   __attribute__((ext_vector_type(4)));
typedef __bf16 bf16x8   __attribute__((ext_vector_type(8)));

__device__ __forceinline__ float b2f(u16 u) {
    return __uint_as_float(((u32)u) << 16);
}
__device__ __forceinline__ u16 f2b(float f) {
    u32 b = __float_as_uint(f);
    b += 0x7fffu + ((b >> 16) & 1u);   // RNE
    return (u16)(b >> 16);
}
__device__ __forceinline__ u32 pk2(float a, float b) {
    return (u32)f2b(a) | ((u32)f2b(b) << 16);
}
__device__ __forceinline__ void unp8(uint4v u, float* f) {
    f[0] = __uint_as_float(u[0] << 16); f[1] = __uint_as_float(u[0] & 0xffff0000u);
    f[2] = __uint_as_float(u[1] << 16); f[3] = __uint_as_float(u[1] & 0xffff0000u);
    f[4] = __uint_as_float(u[2] << 16); f[5] = __uint_as_float(u[2] & 0xffff0000u);
    f[6] = __uint_as_float(u[3] << 16); f[7] = __uint_as_float(u[3] & 0xffff0000u);
}

// ---------------------------------------------------------------------------
// GEMM (bf16 MFMA, fp32 accum): out[M=4096, n] = X[4096,512] @ W[512,n] + bias
// kind==0: X fp32, fused QKV, grid.y=24. blay==1 (MFMA-attn layouts):
//   q -> bf16 [m][512] pre-scaled; k -> bf16 [m][512] plain (B-frag shaped);
//   v -> bf16 vt[b][h][d][n] (transposed, PV B-frag shaped).
// blay==0 (fallback layouts): q fp32, k blocked kb[b][h][c][n][z], v plain.
// kind==1: X bf16 (attn out), O-projection, grid.y=8, writes fp32 d_out.
// ---------------------------------------------------------------------------
__global__ __launch_bounds__(256) void gemm_kernel(
    const float* __restrict__ Xf, const u16* __restrict__ Xb,
    const float* __restrict__ W0, const float* __restrict__ W1, const float* __restrict__ W2,
    const float* __restrict__ Bq, const float* __restrict__ Bk, const float* __restrict__ Bv,
    float* __restrict__ qoutf, u16* __restrict__ qout16,
    u16* __restrict__ kout, u16* __restrict__ vout,
    float* __restrict__ fout,
    const float* __restrict__ ctk, const int* __restrict__ ct, int kind, int blay)
{
    __shared__ u16 lx[128 * 40];   // [m][k] bf16, stride 40 (80B rows, 16B aligned)
    __shared__ u16 lw[64 * 40];    // [n][k] bf16 (W transposed), stride 40

    const int t  = threadIdx.x;
    const int m0 = blockIdx.x * 128;
    const int n0g = blockIdx.y * 64;

    int mode, cl0;
    const float* W; const float* Bi;
    if (kind == 0) {
        mode = n0g >> 9; cl0 = n0g & 511;
        W  = (mode == 0) ? W0 : ((mode == 1) ? W1 : W2);
        Bi = (mode == 0) ? Bq : ((mode == 1) ? Bk : Bv);
    } else {
        mode = 3; cl0 = n0g; W = W0; Bi = Bq;
    }

    const int wv = t >> 6, lane = t & 63, quad = lane >> 4, l16 = lane & 15;

    float4_t acc[2][4];
    #pragma unroll
    for (int mi = 0; mi < 2; ++mi)
        #pragma unroll
        for (int ni = 0; ni < 4; ++ni) {
            float4_t z = {0.f, 0.f, 0.f, 0.f};
            acc[mi][ni] = z;
        }

    for (int k0 = 0; k0 < 512; k0 += 32) {
        if (kind == 0) {
            #pragma unroll
            for (int half = 0; half < 2; ++half) {
                const int c = t + half * 256;
                const int r = c >> 2, ck = c & 3;
                const float* src = &Xf[(m0 + r) * 512 + k0 + ck * 8];
                float4_t a0 = *(const float4_t*)src;
                float4_t a1 = *(const float4_t*)(src + 4);
                uint4v p;
                p[0] = pk2(a0[0], a0[1]); p[1] = pk2(a0[2], a0[3]);
                p[2] = pk2(a1[0], a1[1]); p[3] = pk2(a1[2], a1[3]);
                *(uint4v*)&lx[r * 40 + ck * 8] = p;
            }
        } else {
            #pragma unroll
            for (int half = 0; half < 2; ++half) {
                const int c = t + half * 256;
                const int r = c >> 2, ck = c & 3;
                *(uint4v*)&lx[r * 40 + ck * 8] =
                    *(const uint4v*)&Xb[(m0 + r) * 512 + k0 + ck * 8];
            }
        }
        {
            const int kl = t >> 3, nc = t & 7;
            const float* src = &W[(k0 + kl) * 512 + cl0 + nc * 8];
            float4_t wa = *(const float4_t*)src;
            float4_t wb = *(const float4_t*)(src + 4);
            lw[(nc * 8 + 0) * 40 + kl] = f2b(wa[0]);
            lw[(nc * 8 + 1) * 40 + kl] = f2b(wa[1]);
            lw[(nc * 8 + 2) * 40 + kl] = f2b(wa[2]);
            lw[(nc * 8 + 3) * 40 + kl] = f2b(wa[3]);
            lw[(nc * 8 + 4) * 40 + kl] = f2b(wb[0]);
            lw[(nc * 8 + 5) * 40 + kl] = f2b(wb[1]);
            lw[(nc * 8 + 6) * 40 + kl] = f2b(wb[2]);
            lw[(nc * 8 + 7) * 40 + kl] = f2b(wb[3]);
        }
        __syncthreads();

        bf16x8 af[2], bfr[4];
        af[0] = *(bf16x8*)&lx[(wv * 32 +      l16) * 40 + quad * 8];
        af[1] = *(bf16x8*)&lx[(wv * 32 + 16 + l16) * 40 + quad * 8];
        #pragma unroll
        for (int ni = 0; ni < 4; ++ni)
            bfr[ni] = *(bf16x8*)&lw[(ni * 16 + l16) * 40 + quad * 8];

        #pragma unroll
        for (int mi = 0; mi < 2; ++mi)
            #pragma unroll
            for (int ni = 0; ni < 4; ++ni)
                acc[mi][ni] = __builtin_amdgcn_mfma_f32_16x16x32_bf16(af[mi], bfr[ni], acc[mi][ni], 0, 0, 0);
        __syncthreads();
    }

    const int b_blk = m0 >> 9;
    #pragma unroll
    for (int ni = 0; ni < 4; ++ni) {
        const int cl = cl0 + ni * 16 + l16;
        const float bias = Bi[cl];
        float ctkv = 0.f;
        if (mode == 1) ctkv = ctk[ct[b_blk] * HID_ + cl];
        #pragma unroll
        for (int mi = 0; mi < 2; ++mi) {
            #pragma unroll
            for (int reg = 0; reg < 4; ++reg) {
                const int gm = m0 + wv * 32 + mi * 16 + quad * 4 + reg;
                float val = acc[mi][ni][reg] + bias;
                if (mode == 0) {
                    if (blay) qout16[gm * 512 + cl] = f2b(val * 0.125f);
                    else      qoutf[gm * 512 + cl] = val * 0.125f;
                } else if (mode == 1) {
                    const float kv = val + ctkv;
                    if (blay) kout[gm * 512 + cl] = f2b(kv);
                    else {
                        const int nn = gm & 511, bb = gm >> 9;
                        const int hh = cl >> 6, cc = (cl >> 3) & 7, zz = cl & 7;
                        kout[((((bb * 8 + hh) * 8 + cc) * 512) + nn) * 8 + zz] = f2b(kv);
                    }
                } else if (mode == 2) {
                    if (blay) {
                        const int nn = gm & 511, bb = gm >> 9;
                        const int hh = cl >> 6, dd = cl & 63;
                        vout[(((long)(bb * 8 + hh) * 64) + dd) * 512 + nn] = f2b(val);
                    } else vout[gm * 512 + cl] = f2b(val);
                } else fout[gm * 512 + cl] = val;
            }
        }
    }
}

// ---------------------------------------------------------------------------
// Edge MLP via MFMA: eb[p,h] = elu(ef[p,:]@We1+be1)@We2+be2, p in [0,2M).
// ---------------------------------------------------------------------------
__global__ __launch_bounds__(256) void edge_kernel(
    const float* __restrict__ ef,
    const float* __restrict__ We1, const float* __restrict__ be1,
    const float* __restrict__ We2, const float* __restrict__ be2,
    u16* __restrict__ eb)
{
    __shared__ u16 lw1[64 * 32];       // B1[n=hidden][k=e]  (We1 transposed)
    __shared__ u16 lw2[16 * 64];       // B2[n=out(8 valid)][k=hidden] (We2^T, padded)
    __shared__ u16 h1t[4][16 * 72];    // per-wave H1 tile [row][k], stride 72

    const int t = threadIdx.x;
    const int wv = t >> 6, lane = t & 63, quad = lane >> 4, l16 = lane & 15;

    for (int i = t; i < 2048; i += 256) {
        const int n = i >> 5, k = i & 31;
        lw1[n * 32 + k] = f2b(We1[k * 64 + n]);
    }
    for (int i = t; i < 1024; i += 256) {
        const int n = i >> 6, k = i & 63;
        lw2[n * 64 + k] = (n < 8) ? f2b(We2[k * 8 + n]) : (u16)0;
    }
    __syncthreads();

    bf16x8 b1[4];
    #pragma unroll
    for (int ni = 0; ni < 4; ++ni)
        b1[ni] = *(bf16x8*)&lw1[(ni * 16 + l16) * 32 + quad * 8];
    bf16x8 b20 = *(bf16x8*)&lw2[l16 * 64 +      quad * 8];
    bf16x8 b21 = *(bf16x8*)&lw2[l16 * 64 + 32 + quad * 8];

    float be1r[4];
    #pragma unroll
    for (int ni = 0; ni < 4; ++ni) be1r[ni] = be1[l16 + 16 * ni];
    const float be2r = (l16 < 8) ? be2[l16] : 0.f;

    for (int tt = 0; tt < 4; ++tt) {
        const long row0g = (long)blockIdx.x * 256 + tt * 64 + wv * 16;

        const float* ap = ef + (row0g + l16) * 32 + quad * 8;
        float4_t f0 = *(const float4_t*)ap;
        float4_t f1 = *(const float4_t*)(ap + 4);
        uint4v au;
        au[0] = pk2(f0[0], f0[1]); au[1] = pk2(f0[2], f0[3]);
        au[2] = pk2(f1[0], f1[1]); au[3] = pk2(f1[2], f1[3]);
        bf16x8 a1 = *(bf16x8*)&au;

        float4_t zero = {0.f, 0.f, 0.f, 0.f};
        float4_t c1[4];
        #pragma unroll
        for (int ni = 0; ni < 4; ++ni)
            c1[ni] = __builtin_amdgcn_mfma_f32_16x16x32_bf16(a1, b1[ni], zero, 0, 0, 0);

        #pragma unroll
        for (int ni = 0; ni < 4; ++ni) {
            #pragma unroll
            for (int reg = 0; reg < 4; ++reg) {
                float v = c1[ni][reg] + be1r[ni];
                v = (v > 0.f) ? v : expm1f(v);
                h1t[wv][(quad * 4 + reg) * 72 + l16 + 16 * ni] = f2b(v);
            }
        }
        __syncthreads();

        bf16x8 a20 = *(bf16x8*)&h1t[wv][l16 * 72 +      quad * 8];
        bf16x8 a21 = *(bf16x8*)&h1t[wv][l16 * 72 + 32 + quad * 8];
        float4_t c2 = zero;
        c2 = __builtin_amdgcn_mfma_f32_16x16x32_bf16(a20, b20, c2, 0, 0, 0);
        c2 = __builtin_amdgcn_mfma_f32_16x16x32_bf16(a21, b21, c2, 0, 0, 0);

        if (l16 < 8) {
            #pragma unroll
            for (int reg = 0; reg < 4; ++reg)
                eb[(row0g + quad * 4 + reg) * 8 + l16] = f2b(c2[reg] + be2r);
        }
        __syncthreads();
    }
}

// ---------------------------------------------------------------------------
// Attention v7 (MFMA): one block per (b, h, 16-q-row tile); 2048 blocks,
// 256 thr = 4 waves. Wave w: keys [w*128, w*128+128) for QK^T (8 n-tiles x
// 2 K-steps = 16 MFMAs), then d-range [w*16, w*16+16) for PV (16 MFMAs).
// Fragment layouts identical to gemm_kernel (HW-validated):
//   A: m=l16, k=quad*8+j.  B: n=l16, k=quad*8+j.  C/D: col=l16, row=quad*4+reg.
// Q/K/V-frags load DIRECT from global (no LDS staging; K rows are B-frag
// shaped, V transposed vt[b][h][d][n]). Softmax in C-layout registers:
// row r lives in quad r/4 across 16 lanes (keys) -> width-16 shfl_xor
// reduction + tiny cross-wave LDS arrays. Zero broadcast LDS reads (the
// r2-r6 scalar kernel issued ~768 broadcast ds_read_b128/wave = its wall).
// P (normalized bf16) staged in [16][520] LDS (pad 520: kills the 16-way
// bank conflict of stride-512) as PV A-frags. mean: coalesced fp32
// atomicAdd (8 h-writers per cell; out1 pre-zeroed by hipMemsetAsync).
// Register budget: sacc 32 + temps; must stay <=64 VGPR (allocator refuses
// more for this family - r3/r4/r6 evidence). Tripwire: WRITE >> 30 MB.
// ---------------------------------------------------------------------------
__global__ __launch_bounds__(256, 4) void attn_mfma_kernel(
    const u16* __restrict__ qws, const u16* __restrict__ kws, const u16* __restrict__ vtws,
    const u16* __restrict__ ebws,
    const int* __restrict__ bmask, const int* __restrict__ pmask,
    u16* __restrict__ attn_out, float* __restrict__ mean_out)
{
    __shared__ u16 P[16][520];
    __shared__ float redm[4][16];
    __shared__ float reds[4][16];

    const int t = threadIdx.x;
    const int w = t >> 6, lane = t & 63, quad = lane >> 4, l16 = lane & 15;
    const int bid = blockIdx.x;
    const int b = bid >> 8, h = (bid >> 5) & 7, qt = bid & 31;
    const long brow0 = (long)b * 512 + qt * 16;

    // Q A-frags (rows q0..q0+15, k=d): direct global, bf16 pre-scaled
    const u16* qp = qws + (brow0 + l16) * 512 + h * 64 + quad * 8;
    const bf16x8 aq0 = *(const bf16x8*)qp;
    const bf16x8 aq1 = *(const bf16x8*)(qp + 32);

    int padr[4];
    #pragma unroll
    for (int reg = 0; reg < 4; ++reg) padr[reg] = pmask[brow0 + quad * 4 + reg];

    // ---- QK^T: 8 n-tiles x (K=64 -> 2 MFMAs) ----
    float4_t sacc[8];
    {
        const u16* kbase = kws + ((long)b * 512 + w * 128) * 512 + h * 64 + quad * 8;
        #pragma unroll
        for (int nt = 0; nt < 8; ++nt) {
            const u16* kp = kbase + (nt * 16 + l16) * 512;
            const bf16x8 kb0 = *(const bf16x8*)kp;
            const bf16x8 kb1 = *(const bf16x8*)(kp + 32);
            float4_t z = {0.f, 0.f, 0.f, 0.f};
            z = __builtin_amdgcn_mfma_f32_16x16x32_bf16(aq0, kb0, z, 0, 0, 0);
            sacc[nt] = __builtin_amdgcn_mfma_f32_16x16x32_bf16(aq1, kb1, z, 0, 0, 0);
        }
    }

    // ---- epilogue: + edge bias, masks; row-max partials ----
    const float NEGINF = -__builtin_inff();
    float m4[4] = {NEGINF, NEGINF, NEGINF, NEGINF};
    #pragma unroll
    for (int nt = 0; nt < 8; ++nt) {
        const int key = w * 128 + nt * 16 + l16;
        const int pj = pmask[b * 512 + key];
        const u16* ebp = ebws + ((brow0 + quad * 4) * 512 + key) * 8 + h;
        const int* bmp = bmask + (brow0 + quad * 4) * 512 + key;
        #pragma unroll
        for (int reg = 0; reg < 4; ++reg) {
            const bool msk = (padr[reg] | pj | bmp[reg * 512]) != 0;
            float s = sacc[nt][reg] + b2f(ebp[reg * 4096]);
            s = msk ? NEGINF : s;
            sacc[nt][reg] = s;
            m4[reg] = fmaxf(m4[reg], s);
        }
    }
    #pragma unroll
    for (int reg = 0; reg < 4; ++reg) {
        #pragma unroll
        for (int off = 8; off >= 1; off >>= 1)
            m4[reg] = fmaxf(m4[reg], __shfl_xor(m4[reg], off, 16));
    }
    if (l16 == 0) {
        #pragma unroll
        for (int reg = 0; reg < 4; ++reg) redm[w][quad * 4 + reg] = m4[reg];
    }
    __syncthreads();
    float rmax[4];
    #pragma unroll
    for (int reg = 0; reg < 4; ++reg) {
        const int r = quad * 4 + reg;
        rmax[reg] = fmaxf(fmaxf(redm[0][r], redm[1][r]), fmaxf(redm[2][r], redm[3][r]));
    }

    // ---- exp + row-sum ----
    float s4[4] = {0.f, 0.f, 0.f, 0.f};
    #pragma unroll
    for (int nt = 0; nt < 8; ++nt) {
        #pragma unroll
        for (int reg = 0; reg < 4; ++reg) {
            const float s = sacc[nt][reg];
            const float e = (s == NEGINF) ? 0.f : __expf(s - rmax[reg]);
            sacc[nt][reg] = e;
            s4[reg] += e;
        }
    }
    #pragma unroll
    for (int reg = 0; reg < 4; ++reg) {
        #pragma unroll
        for (int off = 8; off >= 1; off >>= 1)
            s4[reg] += __shfl_xor(s4[reg], off, 16);
    }
    if (l16 == 0) {
        #pragma unroll
        for (int reg = 0; reg < 4; ++reg) reds[w][quad * 4 + reg] = s4[reg];
    }
    __syncthreads();
    float invZ[4];
    #pragma unroll
    for (int reg = 0; reg < 4; ++reg) {
        const int r = quad * 4 + reg;
        const float Z = (reds[0][r] + reds[1][r]) + (reds[2][r] + reds[3][r]);
        invZ[reg] = (Z > 0.f) ? (1.f / Z) : 0.f;
    }

    // ---- normalize: P bf16 -> LDS; mean contribution via atomicAdd ----
    #pragma unroll
    for (int nt = 0; nt < 8; ++nt) {
        const int key = w * 128 + nt * 16 + l16;
        #pragma unroll
        for (int reg = 0; reg < 4; ++reg) {
            const float p = sacc[nt][reg] * invZ[reg];
            P[quad * 4 + reg][key] = f2b(p);
            atomicAdd(&mean_out[(brow0 + quad * 4 + reg) * 512 + key], p * 0.125f);
        }
    }
    __syncthreads();

    // ---- PV: wave w covers d in [w*16, w*16+16); 16 K-steps of 32 keys ----
    {
        float4_t oacc = {0.f, 0.f, 0.f, 0.f};
        const u16* vp = vtws + (((long)b * 8 + h) * 64 + w * 16 + l16) * 512;
        #pragma unroll
        for (int kt = 0; kt < 16; ++kt) {
            const bf16x8 pa = *(const bf16x8*)&P[l16][kt * 32 + quad * 8];
            const bf16x8 vb = *(const bf16x8*)(vp + kt * 32 + quad * 8);
            oacc = __builtin_amdgcn_mfma_f32_16x16x32_bf16(pa, vb, oacc, 0, 0, 0);
        }
        #pragma unroll
        for (int reg = 0; reg < 4; ++reg)
            attn_out[(brow0 + quad * 4 + reg) * 512 + h * 64 + w * 16 + l16] = f2b(oacc[reg]);
    }
}

// ---------------------------------------------------------------------------
// Fallback fused attention for small ws_size (r5-proven path; blay==0
// layouts: q fp32, blocked K, plain V).
// ---------------------------------------------------------------------------
__global__ __launch_bounds__(256) void attn_fused_kernel(
    const float* __restrict__ qws, const u16* __restrict__ kws, const u16* __restrict__ vws,
    const float* __restrict__ ef,
    const float* __restrict__ We1, const float* __restrict__ be1,
    const float* __restrict__ We2, const float* __restrict__ be2,
    const int* __restrict__ bmask, const int* __restrict__ pmask,
    u16* __restrict__ attn_out, float* __restrict__ mean_out)
{
    __shared__ float ql[2 * 512];
    __shared__ float S[2][8][512];
    __shared__ __align__(16) float wf[2632];

    const int t = threadIdx.x;
    const int b = blockIdx.x >> 8;
    const int i0 = (blockIdx.x & 255) * 2;
    const int row0 = b * N_ + i0;

    for (int i = t; i < 2632; i += 256) {
        float v;
        if (i < 2048)      v = We1[i];
        else if (i < 2112) v = be1[i - 2048];
        else if (i < 2624) v = We2[i - 2112];
        else               v = be2[i - 2624];
        wf[i] = v;
    }
    *(float4_t*)&ql[t * 4] = *(const float4_t*)&qws[row0 * 512 + t * 4];

    const int padi0 = pmask[b * N_ + i0];
    const int padi1 = pmask[b * N_ + i0 + 1];
    __syncthreads();

    const float4_t* We1v = (const float4_t*)wf;
    const float4_t* be1v = (const float4_t*)(wf + 2048);
    const float4_t* We2v = (const float4_t*)(wf + 2112);
    const float4_t* be2v = (const float4_t*)(wf + 2624);

    for (int jj = t; jj < 512; jj += 256) {
        const int pj  = pmask[b * N_ + jj];
        const int bm0 = bmask[row0 * 512 + jj];
        const int bm1 = bmask[(row0 + 1) * 512 + jj];
        const bool msk0 = (padi0 | pj | bm0) != 0;
        const bool msk1 = (padi1 | pj | bm1) != 0;

        float x0[32], x1[32];
        {
            const float4_t* p0 = (const float4_t*)(ef + ((long)row0       * 512 + jj) * 32);
            const float4_t* p1 = (const float4_t*)(ef + ((long)(row0 + 1) * 512 + jj) * 32);
            #pragma unroll
            for (int c = 0; c < 8; ++c) {
                float4_t a = p0[c], bb = p1[c];
                #pragma unroll
                for (int z = 0; z < 4; ++z) { x0[c * 4 + z] = a[z]; x1[c * 4 + z] = bb[z]; }
            }
        }

        float e0[8], e1[8];
        {
            float4_t o0a = be2v[0], o0b = be2v[1];
            float4_t o1a = o0a,     o1b = o0b;
            #pragma unroll 1
            for (int o4 = 0; o4 < 16; ++o4) {
                float4_t h0 = be1v[o4], h1 = h0;
                #pragma unroll
                for (int e = 0; e < 32; ++e) {
                    const float4_t w = We1v[e * 16 + o4];
                    const float xe0 = x0[e], xe1 = x1[e];
                    #pragma unroll
                    for (int z = 0; z < 4; ++z) {
                        h0[z] = fmaf(xe0, w[z], h0[z]);
                        h1[z] = fmaf(xe1, w[z], h1[z]);
                    }
                }
                #pragma unroll
                for (int z = 0; z < 4; ++z) {
                    h0[z] = (h0[z] > 0.f) ? h0[z] : expm1f(h0[z]);
                    h1[z] = (h1[z] > 0.f) ? h1[z] : expm1f(h1[z]);
                }
                #pragma unroll
                for (int z = 0; z < 4; ++z) {
                    const int o = o4 * 4 + z;
                    const float4_t wa = We2v[o * 2], wb = We2v[o * 2 + 1];
                    #pragma unroll
                    for (int p = 0; p < 4; ++p) {
                        o0a[p] = fmaf(h0[z], wa[p], o0a[p]);
                        o0b[p] = fmaf(h0[z], wb[p], o0b[p]);
                        o1a[p] = fmaf(h1[z], wa[p], o1a[p]);
                        o1b[p] = fmaf(h1[z], wb[p], o1b[p]);
                    }
                }
            }
            #pragma unroll
            for (int p = 0; p < 4; ++p) {
                e0[p] = o0a[p]; e0[p + 4] = o0b[p];
                e1[p] = o1a[p]; e1[p + 4] = o1b[p];
            }
        }

        const u16* kb = kws + (long)b * 262144 + jj * 8;
        #pragma unroll 1
        for (int h = 0; h < 8; ++h) {
            float d0 = 0.f, d1 = 0.f;
            #pragma unroll
            for (int c = 0; c < 8; ++c) {
                uint4v u = *(const uint4v*)(kb + (h * 8 + c) * 4096);
                float kf[8]; unp8(u, kf);
                const float* q0 = &ql[h * 64 + c * 8];
                const float* q1 = &ql[512 + h * 64 + c * 8];
                #pragma unroll
                for (int z = 0; z < 8; ++z) {
                    d0 = fmaf(kf[z], q0[z], d0);
                    d1 = fmaf(kf[z], q1[z], d1);
                }
            }
            S[0][h][jj] = msk0 ? -__builtin_inff() : (d0 + e0[h]);
            S[1][h][jj] = msk1 ? -__builtin_inff() : (d1 + e1[h]);
        }
    }
    __syncthreads();

    {
        const int h = t >> 5, l = t & 31;
        #pragma unroll
        for (int r = 0; r < 2; ++r) {
            float m = -__builtin_inff();
            for (int kk = 0; kk < 16; ++kk) m = fmaxf(m, S[r][h][l + 32 * kk]);
            #pragma unroll
            for (int off = 16; off >= 1; off >>= 1) m = fmaxf(m, __shfl_xor(m, off, 32));

            float zsum = 0.f;
            for (int kk = 0; kk < 16; ++kk) {
                const int j = l + 32 * kk;
                const float s = S[r][h][j];
                const float e = (s == -__builtin_inff()) ? 0.f : __expf(s - m);
                S[r][h][j] = e;
                zsum += e;
            }
            #pragma unroll
            for (int off = 16; off >= 1; off >>= 1) zsum += __shfl_xor(zsum, off, 32);

            const float inv = (zsum > 0.f) ? (1.f / zsum) : 0.f;
            for (int kk = 0; kk < 16; ++kk) S[r][h][l + 32 * kk] *= inv;
        }
    }
    __syncthreads();

    for (int jj = t; jj < 512; jj += 256) {
        #pragma unroll
        for (int r = 0; r < 2; ++r) {
            float sum = 0.f;
            #pragma unroll
            for (int h = 0; h < 8; ++h) sum += S[r][h][jj];
            mean_out[(long)(row0 + r) * 512 + jj] = sum * 0.125f;
        }
    }

    {
        const int h = t >> 5, d0 = (t & 31) * 2;
        float a00 = 0.f, a01 = 0.f, a10 = 0.f, a11 = 0.f;
        const u16* vp = vws + (long)(b * N_) * 512 + h * 64 + d0;
        #pragma unroll 4
        for (int j = 0; j < 512; ++j) {
            const u32 u = *(const u32*)(vp + (long)j * 512);
            const float v0 = __uint_as_float(u << 16);
            const float v1 = __uint_as_float(u & 0xffff0000u);
            const float p0 = S[0][h][j];
            const float p1 = S[1][h][j];
            a00 = fmaf(p0, v0, a00); a01 = fmaf(p0, v1, a01);
            a10 = fmaf(p1, v0, a10); a11 = fmaf(p1, v1, a11);
        }
        *(u32*)&attn_out[(long)row0       * 512 + h * 64 + d0] = pk2(a00, a01);
        *(u32*)&attn_out[(long)(row0 + 1) * 512 + h * 64 + d0] = pk2(a10, a11);
    }
}

// ---------------------------------------------------------------------------
extern "C" void kernel_launch(void* const* d_in, const int* in_sizes, int n_in,
                              void* d_out, int out_size, void* d_ws, size_t ws_size,
                              hipStream_t stream) {
    const float* x   = (const float*)d_in[0];
    const int*   ct  = (const int*)d_in[1];
    const float* ef  = (const float*)d_in[2];
    const int*   bm  = (const int*)d_in[3];
    const int*   pm  = (const int*)d_in[4];
    const float* Wq  = (const float*)d_in[5];  const float* bq = (const float*)d_in[6];
    const float* Wk  = (const float*)d_in[7];  const float* bk = (const float*)d_in[8];
    const float* Wv  = (const float*)d_in[9];  const float* bv = (const float*)d_in[10];
    const float* Wo  = (const float*)d_in[11]; const float* bo = (const float*)d_in[12];
    const float* We1 = (const float*)d_in[13]; const float* be1 = (const float*)d_in[14];
    const float* We2 = (const float*)d_in[15]; const float* be2 = (const float*)d_in[16];
    const float* ctk = (const float*)d_in[17];
    // d_in[18] = ct_bias_emb: constant along softmax axis -> cancels; unused.

    char* ws = (char*)d_ws;
    float* out0 = (float*)d_out;        // (B,N,HID) fp32
    float* out1 = out0 + 2097152;       // (B,N,N)  fp32 attn mean
    const size_t WS_BIG = 54525952;

    if (ws_size >= WS_BIG) {
        // MFMA-attn layouts
        u16* qws  = (u16*)ws;                    // 4 MB bf16 [m][512], pre-scaled
        u16* kws  = (u16*)(ws + 4194304);        // 4 MB bf16 [m][512] (+ct_key)
        u16* vt   = (u16*)(ws + 8388608);        // 4 MB bf16 vt[b][h][d][n]
        u16* aout = (u16*)(ws + 12582912);       // 4 MB bf16 attn out [m][512]
        u16* ebws = (u16*)(ws + 16777216);       // 32 MB bf16 edge bias

        hipMemsetAsync(out1, 0, 8388608, stream);   // mean accumulated by atomics
        gemm_kernel<<<dim3(32, 24), 256, 0, stream>>>(x, nullptr, Wq, Wk, Wv, bq, bk, bv,
                                                      nullptr, qws, kws, vt, out0, ctk, ct, 0, 1);
        edge_kernel<<<8192, 256, 0, stream>>>(ef, We1, be1, We2, be2, ebws);
        attn_mfma_kernel<<<2048, 256, 0, stream>>>(qws, kws, vt, ebws, bm, pm, aout, out1);
        gemm_kernel<<<dim3(32, 8), 256, 0, stream>>>(nullptr, aout, Wo, Wo, Wo, bo, bo, bo,
                                                     nullptr, nullptr, nullptr, nullptr, out0,
                                                     ctk, ct, 1, 0);
    } else {
        // fallback layouts (r5-proven)
        float* qwsf = (float*)ws;                 //  8 MB fp32, pre-scaled
        u16*   kwsb = (u16*)(ws + 8388608);       //  4 MB bf16 blocked (+ct_key)
        u16*   vws  = (u16*)(ws + 12582912);      //  4 MB bf16 plain
        u16*   aout = (u16*)(ws + 16777216);      //  4 MB bf16 attn out

        gemm_kernel<<<dim3(32, 24), 256, 0, stream>>>(x, nullptr, Wq, Wk, Wv, bq, bk, bv,
                                                      qwsf, nullptr, kwsb, vws, out0, ctk, ct, 0, 0);
        attn_fused_kernel<<<2048, 256, 0, stream>>>(qwsf, kwsb, vws, ef, We1, be1, We2, be2,
                                                    bm, pm, aout, out1);
        gemm_kernel<<<dim3(32, 8), 256, 0, stream>>>(nullptr, aout, Wo, Wo, Wo, bo, bo, bo,
                                                     nullptr, nullptr, nullptr, nullptr, out0,
                                                     ctk, ct, 1, 0);
    }
}